// Round 11
// baseline (221.472 us; speedup 1.0000x reference)
//
#include <hip/hip_runtime.h>

#define D_   256
#define HW_  1024
#define N_   32768
#define K_   1024

#define MAXREF  8192
#define QMARGIN 5.0e-5f   // flag margin, s-units
#define RMARGIN 4.0e-5f   // refine qualification vs screen-min, s-units

typedef __attribute__((ext_vector_type(8))) short short8v;  // 8 bf16 (4 VGPRs)
typedef __attribute__((ext_vector_type(4))) float f32x4;    // MFMA acc

// ws layout (bytes):
//   0       counter (int)
//   1024    list[MAXREF] ints          (32 KB)
//   33792   B32[1024] floats           (4 KB)
//   37888   A32[32768] floats          (128 KB)
//   168960  cbAhi fragments            (512 KB)
//   693248  cbAlo fragments            (512 KB)
//   1217536 vlist[MAXREF] floats       (32 KB)
//   1250304 cell[MAXREF] u64           (64 KB)   end ~1.26 MB
//
// zq-region scratch: zBhi | zBlo  (b-frag-ordered bf16 z, 16 MB + 16 MB =
// exactly the zq size; consumed by screen, overwritten by gather at the end)

// ---------------------------------------------------------------------------
__device__ __forceinline__ unsigned short f2bf_rne(float f) {
    unsigned u = __float_as_uint(f);
    unsigned r = u + 0x7FFFu + ((u >> 16) & 1u);
    return (unsigned short)(r >> 16);
}
__device__ __forceinline__ float bf2f(unsigned short h) {
    return __uint_as_float(((unsigned)h) << 16);
}

// numpy pairwise fp32 sum of squares over 256 elements (stride in elems).
__device__ __forceinline__ float np_sumsq_256(const float* a, int stride) {
    float blk[2];
    #pragma unroll
    for (int h = 0; h < 2; ++h) {
        const float* p = a + (size_t)h * 128 * stride;
        float r[8];
        #pragma unroll
        for (int j = 0; j < 8; ++j) {
            float v = p[(size_t)j * stride];
            r[j] = __fmul_rn(v, v);
        }
        for (int i = 1; i < 16; ++i) {
            #pragma unroll
            for (int j = 0; j < 8; ++j) {
                float v = p[(size_t)(i * 8 + j) * stride];
                r[j] = __fadd_rn(r[j], __fmul_rn(v, v));
            }
        }
        blk[h] = __fadd_rn(__fadd_rn(__fadd_rn(r[0], r[1]), __fadd_rn(r[2], r[3])),
                           __fadd_rn(__fadd_rn(r[4], r[5]), __fadd_rn(r[6], r[7])));
    }
    return __fadd_rn(blk[0], blk[1]);
}

// ---------------------------------------------------------------------------
// Fused prep: bnorm(0-3) | anorm(4-131) | cbsplit(132-259) | init(260) |
// zfrag(261-4356): b-frag-ordered bf16 hi/lo split of z.
// zB chunk c = (pxg*8+ds)*64 + lane, lane=q*16+r: holds z[px=pxg*16+r][d=ds*32+q*8+j]
// ---------------------------------------------------------------------------
__global__ __launch_bounds__(256) void prep_kernel(const float* __restrict__ z,
                                                   const float* __restrict__ cb,
                                                   float* __restrict__ A32,
                                                   float* __restrict__ B32,
                                                   short* __restrict__ cbAhi,
                                                   short* __restrict__ cbAlo,
                                                   short8v* __restrict__ zBhi,
                                                   short8v* __restrict__ zBlo,
                                                   int* __restrict__ counter) {
    const int blk = blockIdx.x;
    const int tid = threadIdx.x;
    if (blk < 4) {
        int k = blk * 256 + tid;
        B32[k] = np_sumsq_256(cb + (size_t)k * D_, 1);
    } else if (blk < 132) {
        int n  = (blk - 4) * 256 + tid;
        int b  = n >> 10;
        int hw = n & 1023;
        A32[n] = np_sumsq_256(z + (size_t)b * (D_ * HW_) + hw, HW_);
    } else if (blk < 260) {
        // fragment-ordered bf16 hi/lo split of codebook (A-operand)
        int c  = (blk - 132) * 256 + tid;   // 0..32767
        int kf = c >> 9;
        int ds = (c >> 6) & 7;
        int q  = (c >> 4) & 3;
        int r  = c & 15;
        int k  = kf * 16 + r;
        int d0 = ds * 32 + q * 8;
        const float* src = cb + (size_t)k * D_ + d0;
        short8v vh, vl;
        #pragma unroll
        for (int j = 0; j < 8; ++j) {
            float f = src[j];
            unsigned short h = f2bf_rne(f);
            float hf = bf2f(h);
            unsigned short l = f2bf_rne(f - hf);
            vh[j] = (short)h;
            vl[j] = (short)l;
        }
        *reinterpret_cast<short8v*>(cbAhi + (size_t)c * 8) = vh;
        *reinterpret_cast<short8v*>(cbAlo + (size_t)c * 8) = vl;
    } else if (blk == 260) {
        if (tid == 0) *counter = 0;
    } else {
        // b-frag-ordered bf16 hi/lo split of z (B-operand)
        int c    = (blk - 261) * 256 + tid;  // 0..1048575
        int pxg  = c >> 9;
        int ds   = (c >> 6) & 7;
        int lane = c & 63;
        int q    = lane >> 4;
        int r    = lane & 15;
        int px   = pxg * 16 + r;
        int bb   = px >> 10;
        int hw   = px & 1023;
        int d0   = ds * 32 + q * 8;
        const float* src = z + (size_t)bb * (D_ * HW_) + hw;
        short8v vh, vl;
        #pragma unroll
        for (int j = 0; j < 8; ++j) {
            float f = src[(size_t)(d0 + j) * HW_];
            unsigned short h = f2bf_rne(f);
            float hf = bf2f(h);
            unsigned short l = f2bf_rne(f - hf);
            vh[j] = (short)h;
            vl[j] = (short)l;
        }
        zBhi[c] = vh;
        zBlo[c] = vl;
    }
}

// ---------------------------------------------------------------------------
// MFMA screening v5: 512 threads (8 waves) = 4 px-groups x 2 K-halves;
// 64 px/block, 512 blocks (2 blocks/CU). b-frags load directly from
// pre-fragmented zB (16 dwordx4 loads, no staging). No per-chunk barrier.
// K-half results merged via tiny LDS exchange; tie-break = lower half wins
// (equivalent to ascending-k first-occurrence).
// ---------------------------------------------------------------------------
__global__ __launch_bounds__(512, 2) void vq_screen5(
        const short8v* __restrict__ zBhi,
        const short8v* __restrict__ zBlo,
        const short8v* __restrict__ cbAhi,
        const short8v* __restrict__ cbAlo,
        const float* __restrict__ B32,
        float* __restrict__ oidx,
        int* __restrict__ counter,
        int* __restrict__ list,
        float* __restrict__ vlist,
        unsigned long long* __restrict__ cell)
{
    __shared__ float halfB[K_];       // 4 KB
    __shared__ float red[2][64][3];   // 1.5 KB

    const int tid  = threadIdx.x;
    const int lane = tid & 63;
    const int wave = tid >> 6;        // 0..7
    const int q    = lane >> 4;       // 0..3
    const int r    = lane & 15;
    const int pxg  = wave >> 1;       // 0..3
    const int kh   = wave & 1;        // K-half

    const int pxgg = blockIdx.x * 4 + pxg;   // global px-group (16 px each)

    halfB[tid]       = 0.5f * B32[tid];
    halfB[512 + tid] = 0.5f * B32[512 + tid];

    // ---- b-frags: direct coalesced loads, statically indexed ----
    short8v bhf[8], blf[8];
    #pragma unroll
    for (int ds = 0; ds < 8; ++ds) {
        bhf[ds] = zBhi[(size_t)(pxgg * 8 + ds) * 64 + lane];
        blf[ds] = zBlo[(size_t)(pxgg * 8 + ds) * 64 + lane];
    }
    __syncthreads();   // halfB ready

    // ---- k-loop over this wave's K-half ----
    float v1 = 3.4e38f, v2v = 3.4e38f;
    int   k1 = 0;

    for (int chl = 0; chl < 16; ++chl) {
        const int ch = kh * 16 + chl;
        f32x4 acc0 = {0.f,0.f,0.f,0.f};
        f32x4 acc1 = {0.f,0.f,0.f,0.f};

        #pragma unroll
        for (int ds = 0; ds < 8; ++ds) {
            int base0 = ((ch * 2 + 0) * 8 + ds) * 64 + lane;
            int base1 = ((ch * 2 + 1) * 8 + ds) * 64 + lane;
            short8v a0h = cbAhi[base0], a0l = cbAlo[base0];
            short8v a1h = cbAhi[base1], a1l = cbAlo[base1];

            acc0 = __builtin_amdgcn_mfma_f32_16x16x32_bf16(a0h, bhf[ds], acc0, 0,0,0);
            acc1 = __builtin_amdgcn_mfma_f32_16x16x32_bf16(a1h, bhf[ds], acc1, 0,0,0);
            acc0 = __builtin_amdgcn_mfma_f32_16x16x32_bf16(a0l, bhf[ds], acc0, 0,0,0);
            acc1 = __builtin_amdgcn_mfma_f32_16x16x32_bf16(a1l, bhf[ds], acc1, 0,0,0);
            acc0 = __builtin_amdgcn_mfma_f32_16x16x32_bf16(a0h, blf[ds], acc0, 0,0,0);
            acc1 = __builtin_amdgcn_mfma_f32_16x16x32_bf16(a1h, blf[ds], acc1, 0,0,0);
        }

        // extraction: D row = q*4+reg (code), col = r (pixel)
        #pragma unroll
        for (int kf = 0; kf < 2; ++kf) {
            int kbase = ch * 32 + kf * 16 + q * 4;
            #pragma unroll
            for (int reg = 0; reg < 4; ++reg) {
                float s = halfB[kbase + reg] - ((kf == 0) ? acc0[reg] : acc1[reg]);
                int  kk = kbase + reg;
                bool lt = s < v1;
                v2v = lt ? v1 : fminf(v2v, s);
                k1  = lt ? kk : k1;
                v1  = lt ? s  : v1;
            }
        }
    }

    // ---- merge the 4 q-groups per pixel (lanes l, l^16, l^32, l^48) ----
    float a1 = v1, a2 = v2v;
    int   ak = k1;
    #pragma unroll
    for (int off = 16; off <= 32; off <<= 1) {
        float o1 = __shfl_xor(a1, off, 64);
        float o2 = __shfl_xor(a2, off, 64);
        int   ok = __shfl_xor(ak, off, 64);
        if (o1 < a1 || (o1 == a1 && ok < ak)) {
            a2 = fminf(a1, o2); a1 = o1; ak = ok;
        } else {
            a2 = fminf(a2, o1);
        }
    }
    if (q == 0) {
        red[kh][pxg * 16 + r][0] = a1;
        red[kh][pxg * 16 + r][1] = __int_as_float(ak);
        red[kh][pxg * 16 + r][2] = a2;
    }
    __syncthreads();

    // ---- K-half merge + output (first 64 threads, one px each) ----
    if (tid < 64) {
        float v0 = red[0][tid][0]; int q0 = __float_as_int(red[0][tid][1]);
        float w0 = red[0][tid][2];
        float v1b = red[1][tid][0]; int q1b = __float_as_int(red[1][tid][1]);
        float w1 = red[1][tid][2];
        float m1; int mk; float m2;
        if (v1b < v0) {            // strict: half0 (lower k) wins ties
            m1 = v1b; mk = q1b; m2 = fminf(w1, v0);
        } else {
            m1 = v0; mk = q0; m2 = fminf(w0, v1b);
        }
        int n = blockIdx.x * 64 + tid;
        oidx[n] = (float)mk;
        if (m2 - m1 < QMARGIN) {
            int slot = atomicAdd(counter, 1);
            if (slot < MAXREF) {
                list[slot]  = n;
                vlist[slot] = m1;
                cell[slot]  = 0xFFFFFFFFFFFFFFFFull;
            }
        }
    }
}

// ---------------------------------------------------------------------------
// Refinement: 8 flagged slots/block; fp32 s for all K, np-emulated d32 for
// qualifying codes, atomicMin packed (d32,k) into cell[slot].
// ---------------------------------------------------------------------------
__global__ __launch_bounds__(256) void refine_np4(const float* __restrict__ z,
                                                  const float* __restrict__ cb,
                                                  const float* __restrict__ A32,
                                                  const float* __restrict__ B32,
                                                  const int* __restrict__ counter,
                                                  const int* __restrict__ list,
                                                  const float* __restrict__ vlist,
                                                  unsigned long long* __restrict__ cell) {
    __shared__ float zs[8][260];
    __shared__ int   pid[8];
    __shared__ float pvref[8];

    const int tid = threadIdx.x;
    int cnt = *counter;
    if (cnt > MAXREF) cnt = MAXREF;
    int i0 = blockIdx.x * 8;
    if (i0 >= cnt) return;

    if (tid < 8) {
        int idx   = i0 + tid;
        int valid = idx < cnt;
        pid[tid]   = list[valid ? idx : i0];
        pvref[tid] = valid ? vlist[idx] : -1e30f;   // invalid: never qualifies
    }
    __syncthreads();

    {   // stage z rows (8 px x 256 d)
        int px = tid >> 5;
        int dl = tid & 31;
        int n  = pid[px];
        int bb = n >> 10, hw = n & 1023;
        const float* zb = z + (size_t)bb * (D_ * HW_) + hw;
        #pragma unroll
        for (int j = 0; j < 8; ++j) {
            int d = dl * 8 + j;
            zs[px][d] = zb[(size_t)d * HW_];
        }
    }
    __syncthreads();

    const int kb = tid * 4;
    float a[4][8];
    #pragma unroll
    for (int jj = 0; jj < 4; ++jj)
        #pragma unroll
        for (int px = 0; px < 8; ++px) a[jj][px] = 0.f;

    for (int d4 = 0; d4 < 64; ++d4) {
        float4 c[4];
        #pragma unroll
        for (int jj = 0; jj < 4; ++jj)
            c[jj] = *reinterpret_cast<const float4*>(cb + (size_t)(kb + jj) * D_ + d4 * 4);
        #pragma unroll
        for (int px = 0; px < 8; ++px) {
            float4 z4 = *reinterpret_cast<const float4*>(&zs[px][d4 * 4]);
            #pragma unroll
            for (int jj = 0; jj < 4; ++jj) {
                a[jj][px] = fmaf(c[jj].x, z4.x, a[jj][px]);
                a[jj][px] = fmaf(c[jj].y, z4.y, a[jj][px]);
                a[jj][px] = fmaf(c[jj].z, z4.z, a[jj][px]);
                a[jj][px] = fmaf(c[jj].w, z4.w, a[jj][px]);
            }
        }
    }

    #pragma unroll
    for (int jj = 0; jj < 4; ++jj) {
        int k = kb + jj;
        float hb = 0.5f * B32[k];
        #pragma unroll
        for (int px = 0; px < 8; ++px) {
            float s = hb - a[jj][px];
            if (s - pvref[px] < RMARGIN) {
                int n = pid[px];
                const float4* crow = reinterpret_cast<const float4*>(cb + (size_t)k * D_);
                double a0 = 0.0, a1 = 0.0, a2 = 0.0, a3 = 0.0;
                for (int d4 = 0; d4 < 64; ++d4) {
                    float4 c4 = crow[d4];
                    a0 = fma((double)c4.x, (double)zs[px][d4 * 4 + 0], a0);
                    a1 = fma((double)c4.y, (double)zs[px][d4 * 4 + 1], a1);
                    a2 = fma((double)c4.z, (double)zs[px][d4 * 4 + 2], a2);
                    a3 = fma((double)c4.w, (double)zs[px][d4 * 4 + 3], a3);
                }
                float C32 = (float)((a0 + a1) + (a2 + a3));
                float d32 = __fsub_rn(__fadd_rn(A32[n], B32[k]), __fadd_rn(C32, C32));
                unsigned long long key =
                    ((unsigned long long)__float_as_uint(d32) << 32) | (unsigned)k;
                atomicMin(&cell[i0 + px], key);
            }
        }
    }
}

// ---------------------------------------------------------------------------
__global__ __launch_bounds__(256) void finalize_kernel(const int* __restrict__ counter,
                                                       const int* __restrict__ list,
                                                       const unsigned long long* __restrict__ cell,
                                                       float* __restrict__ oidx) {
    int cnt = *counter;
    if (cnt > MAXREF) cnt = MAXREF;
    for (int i = blockIdx.x * 256 + threadIdx.x; i < cnt; i += gridDim.x * 256) {
        oidx[list[i]] = (float)(unsigned)(cell[i] & 0xFFFFFFFFull);
    }
}

// ---------------------------------------------------------------------------
__global__ __launch_bounds__(256) void gather_kernel(const float* __restrict__ cb,
                                                     const float* __restrict__ oidx,
                                                     float* __restrict__ zq) {
    const int tid  = threadIdx.x;
    const int s_nl = tid & 63;
    const int s_dw = tid >> 6;
    const int p0   = blockIdx.x * 64;
    const int b    = p0 >> 10;
    const int hw0  = p0 & 1023;

    int idxn = (int)oidx[p0 + s_nl];
    const float4* crow = reinterpret_cast<const float4*>(cb + (size_t)idxn * D_);
    float* zqb = zq + (size_t)b * (D_ * HW_) + hw0;
    #pragma unroll
    for (int r = 0; r < 16; ++r) {
        int d4 = s_dw * 16 + r;
        float4 c4 = crow[d4];
        int d = d4 * 4;
        zqb[(size_t)(d + 0) * HW_ + s_nl] = c4.x;
        zqb[(size_t)(d + 1) * HW_ + s_nl] = c4.y;
        zqb[(size_t)(d + 2) * HW_ + s_nl] = c4.z;
        zqb[(size_t)(d + 3) * HW_ + s_nl] = c4.w;
    }
}

extern "C" void kernel_launch(void* const* d_in, const int* in_sizes, int n_in,
                              void* d_out, int out_size, void* d_ws, size_t ws_size,
                              hipStream_t stream) {
    const float* z  = (const float*)d_in[0];   // [32,256,32,32] fp32
    const float* cb = (const float*)d_in[1];   // [1024,256] fp32

    float* zq   = (float*)d_out;
    float* oidx = zq + (size_t)N_ * D_;

    char* ws = (char*)d_ws;
    int*                counter = (int*)(ws + 0);
    int*                list    = (int*)(ws + 1024);
    float*              B32     = (float*)(ws + 33792);
    float*              A32     = (float*)(ws + 37888);
    short*              cbAhi   = (short*)(ws + 168960);
    short*              cbAlo   = (short*)(ws + 693248);
    float*              vlist   = (float*)(ws + 1217536);
    unsigned long long* cell    = (unsigned long long*)(ws + 1250304);

    // z b-frags live in the zq region (exactly 32 MB), overwritten by gather
    short8v* zBhi = (short8v*)zq;              // 1048576 x 16B
    short8v* zBlo = zBhi + 1048576;            // 1048576 x 16B

    prep_kernel<<<4357, 256, 0, stream>>>(z, cb, A32, B32, cbAhi, cbAlo,
                                          zBhi, zBlo, counter);
    vq_screen5<<<N_ / 64, 512, 0, stream>>>(
        zBhi, zBlo, (const short8v*)cbAhi, (const short8v*)cbAlo, B32,
        oidx, counter, list, vlist, cell);
    refine_np4<<<MAXREF / 8, 256, 0, stream>>>(z, cb, A32, B32, counter, list, vlist, cell);
    finalize_kernel<<<32, 256, 0, stream>>>(counter, list, cell, oidx);
    gather_kernel<<<N_ / 64, 256, 0, stream>>>(cb, oidx, zq);
}

// Round 12
// 174.204 us; speedup vs baseline: 1.2713x; 1.2713x over previous
//
#include <hip/hip_runtime.h>

#define D_   256
#define HW_  1024
#define N_   32768
#define K_   1024

#define MAXREF  8192
#define QMARGIN 5.0e-5f   // flag margin, s-units
#define RMARGIN 4.0e-5f   // refine qualification vs screen-min, s-units

typedef __attribute__((ext_vector_type(8))) short short8v;  // 8 bf16 (4 VGPRs)
typedef __attribute__((ext_vector_type(4))) float f32x4;    // MFMA acc

// async global->LDS, width 16 (guide: m97 pattern). LDS dest must be
// wave-uniform base; global src is per-lane.
#define GLDS(g, l) __builtin_amdgcn_global_load_lds( \
    (const __attribute__((address_space(1))) unsigned int*)(g), \
    (__attribute__((address_space(3))) unsigned int*)(l), 16, 0, 0)

// ws layout (bytes) — unchanged from R11:
//   0       counter | 1024 list[8192] | 33792 B32 | 37888 A32
//   168960  cbAhi (512 KB) | 693248 cbAlo (512 KB)
//   1217536 vlist | 1250304 cell[8192] u64   end ~1.26 MB
// zq-region scratch: zBhi | zBlo (32 MB, consumed by screen, overwritten by gather)

// ---------------------------------------------------------------------------
__device__ __forceinline__ unsigned short f2bf_rne(float f) {
    unsigned u = __float_as_uint(f);
    unsigned r = u + 0x7FFFu + ((u >> 16) & 1u);
    return (unsigned short)(r >> 16);
}
__device__ __forceinline__ float bf2f(unsigned short h) {
    return __uint_as_float(((unsigned)h) << 16);
}

// numpy pairwise fp32 sum of squares over 256 elements (stride in elems).
__device__ __forceinline__ float np_sumsq_256(const float* a, int stride) {
    float blk[2];
    #pragma unroll
    for (int h = 0; h < 2; ++h) {
        const float* p = a + (size_t)h * 128 * stride;
        float r[8];
        #pragma unroll
        for (int j = 0; j < 8; ++j) {
            float v = p[(size_t)j * stride];
            r[j] = __fmul_rn(v, v);
        }
        for (int i = 1; i < 16; ++i) {
            #pragma unroll
            for (int j = 0; j < 8; ++j) {
                float v = p[(size_t)(i * 8 + j) * stride];
                r[j] = __fadd_rn(r[j], __fmul_rn(v, v));
            }
        }
        blk[h] = __fadd_rn(__fadd_rn(__fadd_rn(r[0], r[1]), __fadd_rn(r[2], r[3])),
                           __fadd_rn(__fadd_rn(r[4], r[5]), __fadd_rn(r[6], r[7])));
    }
    return __fadd_rn(blk[0], blk[1]);
}

// ---------------------------------------------------------------------------
// Fused prep (unchanged from R11): bnorm(0-3) | anorm(4-131) | cbsplit(132-259)
// | init(260) | zfrag(261-4356)
// ---------------------------------------------------------------------------
__global__ __launch_bounds__(256) void prep_kernel(const float* __restrict__ z,
                                                   const float* __restrict__ cb,
                                                   float* __restrict__ A32,
                                                   float* __restrict__ B32,
                                                   short* __restrict__ cbAhi,
                                                   short* __restrict__ cbAlo,
                                                   short8v* __restrict__ zBhi,
                                                   short8v* __restrict__ zBlo,
                                                   int* __restrict__ counter) {
    const int blk = blockIdx.x;
    const int tid = threadIdx.x;
    if (blk < 4) {
        int k = blk * 256 + tid;
        B32[k] = np_sumsq_256(cb + (size_t)k * D_, 1);
    } else if (blk < 132) {
        int n  = (blk - 4) * 256 + tid;
        int b  = n >> 10;
        int hw = n & 1023;
        A32[n] = np_sumsq_256(z + (size_t)b * (D_ * HW_) + hw, HW_);
    } else if (blk < 260) {
        int c  = (blk - 132) * 256 + tid;   // 0..32767
        int kf = c >> 9;
        int ds = (c >> 6) & 7;
        int q  = (c >> 4) & 3;
        int r  = c & 15;
        int k  = kf * 16 + r;
        int d0 = ds * 32 + q * 8;
        const float* src = cb + (size_t)k * D_ + d0;
        short8v vh, vl;
        #pragma unroll
        for (int j = 0; j < 8; ++j) {
            float f = src[j];
            unsigned short h = f2bf_rne(f);
            float hf = bf2f(h);
            unsigned short l = f2bf_rne(f - hf);
            vh[j] = (short)h;
            vl[j] = (short)l;
        }
        *reinterpret_cast<short8v*>(cbAhi + (size_t)c * 8) = vh;
        *reinterpret_cast<short8v*>(cbAlo + (size_t)c * 8) = vl;
    } else if (blk == 260) {
        if (tid == 0) *counter = 0;
    } else {
        int c    = (blk - 261) * 256 + tid;  // 0..1048575
        int pxg  = c >> 9;
        int ds   = (c >> 6) & 7;
        int lane = c & 63;
        int q    = lane >> 4;
        int r    = lane & 15;
        int px   = pxg * 16 + r;
        int bb   = px >> 10;
        int hw   = px & 1023;
        int d0   = ds * 32 + q * 8;
        const float* src = z + (size_t)bb * (D_ * HW_) + hw;
        short8v vh, vl;
        #pragma unroll
        for (int j = 0; j < 8; ++j) {
            float f = src[(size_t)(d0 + j) * HW_];
            unsigned short h = f2bf_rne(f);
            float hf = bf2f(h);
            unsigned short l = f2bf_rne(f - hf);
            vh[j] = (short)h;
            vl[j] = (short)l;
        }
        zBhi[c] = vh;
        zBlo[c] = vl;
    }
}

// ---------------------------------------------------------------------------
// MFMA screening v6: 256 thr (4 waves) x 64 px, full K. Per 32-code chunk the
// block stages the 32KB hi+lo a-frag slab into double-buffered LDS ONCE
// (global_load_lds, async) and all 4 waves ds_read_b128 from it — 8x less
// L2 traffic than per-wave streaming (R11's measured bottleneck).
// ---------------------------------------------------------------------------
__global__ __launch_bounds__(256, 2) void vq_screen6(
        const short8v* __restrict__ zBhi,
        const short8v* __restrict__ zBlo,
        const short8v* __restrict__ cbAhi,
        const short8v* __restrict__ cbAlo,
        const float* __restrict__ B32,
        float* __restrict__ oidx,
        int* __restrict__ counter,
        int* __restrict__ list,
        float* __restrict__ vlist,
        unsigned long long* __restrict__ cell)
{
    __shared__ short8v abuf[2][2048];   // [buf][hi 0..1023 | lo 1024..2047], 64KB

    const int tid  = threadIdx.x;
    const int lane = tid & 63;
    const int wave = tid >> 6;        // 0..3
    const int q    = lane >> 4;
    const int r    = lane & 15;

    const int pxgg = blockIdx.x * 4 + wave;   // global 16-px group

    // ---- b-frags: direct coalesced loads (layout unchanged from R11) ----
    short8v bhf[8], blf[8];
    #pragma unroll
    for (int ds = 0; ds < 8; ++ds) {
        bhf[ds] = zBhi[(size_t)(pxgg * 8 + ds) * 64 + lane];
        blf[ds] = zBlo[(size_t)(pxgg * 8 + ds) * 64 + lane];
    }

    // staging roles: waves 0,1 -> hi slab; waves 2,3 -> lo slab; 8KB each
    const char* gbase = (wave < 2 ? (const char*)cbAhi : (const char*)cbAlo)
                      + (wave & 1) * 8192 + lane * 16;
    const int   ldsOff = (wave < 2 ? 0 : 1024) + (wave & 1) * 512;  // short8v units

    // prologue: stage chunk 0 into buf 0
    {
        char* d = (char*)&abuf[0][ldsOff];
        #pragma unroll
        for (int i = 0; i < 8; ++i) GLDS(gbase + i * 1024, d + i * 1024);
    }
    __syncthreads();

    float v1 = 3.4e38f, v2v = 3.4e38f;
    int   k1 = 0;

    for (int ch = 0; ch < 32; ++ch) {
        const int cur = ch & 1;
        if (ch < 31) {   // async-stage next chunk into the other buffer
            const char* s = gbase + (size_t)(ch + 1) * 16384;
            char* d = (char*)&abuf[cur ^ 1][ldsOff];
            #pragma unroll
            for (int i = 0; i < 8; ++i) GLDS(s + i * 1024, d + i * 1024);
        }

        // compute chunk ch from LDS: 2 interleaved acc chains (kf0, kf1)
        f32x4 acc0 = {0.f,0.f,0.f,0.f};
        f32x4 acc1 = {0.f,0.f,0.f,0.f};
        #pragma unroll
        for (int ds = 0; ds < 8; ++ds) {
            short8v a0h = abuf[cur][(0 * 8 + ds) * 64 + lane];
            short8v a0l = abuf[cur][1024 + (0 * 8 + ds) * 64 + lane];
            short8v a1h = abuf[cur][(1 * 8 + ds) * 64 + lane];
            short8v a1l = abuf[cur][1024 + (1 * 8 + ds) * 64 + lane];

            acc0 = __builtin_amdgcn_mfma_f32_16x16x32_bf16(a0h, bhf[ds], acc0, 0,0,0);
            acc1 = __builtin_amdgcn_mfma_f32_16x16x32_bf16(a1h, bhf[ds], acc1, 0,0,0);
            acc0 = __builtin_amdgcn_mfma_f32_16x16x32_bf16(a0l, bhf[ds], acc0, 0,0,0);
            acc1 = __builtin_amdgcn_mfma_f32_16x16x32_bf16(a1l, bhf[ds], acc1, 0,0,0);
            acc0 = __builtin_amdgcn_mfma_f32_16x16x32_bf16(a0h, blf[ds], acc0, 0,0,0);
            acc1 = __builtin_amdgcn_mfma_f32_16x16x32_bf16(a1h, blf[ds], acc1, 0,0,0);
        }

        // extraction (same (kf,reg) scan order as R10/R11): row=q*4+reg, col=r
        #pragma unroll
        for (int kf = 0; kf < 2; ++kf) {
            int kbase = ch * 32 + kf * 16 + q * 4;
            #pragma unroll
            for (int reg = 0; reg < 4; ++reg) {
                float s = 0.5f * B32[kbase + reg] - ((kf == 0) ? acc0[reg] : acc1[reg]);
                int  kk = kbase + reg;
                bool lt = s < v1;
                v2v = lt ? v1 : fminf(v2v, s);
                k1  = lt ? kk : k1;
                v1  = lt ? s  : v1;
            }
        }
        __syncthreads();   // drains stage loads (vmcnt) + buffer handoff
    }

    // ---- merge the 4 q-groups per pixel (lanes l, l^16, l^32, l^48) ----
    float a1 = v1, a2 = v2v;
    int   ak = k1;
    #pragma unroll
    for (int off = 16; off <= 32; off <<= 1) {
        float o1 = __shfl_xor(a1, off, 64);
        float o2 = __shfl_xor(a2, off, 64);
        int   ok = __shfl_xor(ak, off, 64);
        if (o1 < a1 || (o1 == a1 && ok < ak)) {
            a2 = fminf(a1, o2); a1 = o1; ak = ok;
        } else {
            a2 = fminf(a2, o1);
        }
    }
    if (q == 0) {
        int n = blockIdx.x * 64 + wave * 16 + r;
        oidx[n] = (float)ak;
        if (a2 - a1 < QMARGIN) {
            int slot = atomicAdd(counter, 1);
            if (slot < MAXREF) {
                list[slot]  = n;
                vlist[slot] = a1;
                cell[slot]  = 0xFFFFFFFFFFFFFFFFull;
            }
        }
    }
}

// ---------------------------------------------------------------------------
// Refinement (unchanged from R11)
// ---------------------------------------------------------------------------
__global__ __launch_bounds__(256) void refine_np4(const float* __restrict__ z,
                                                  const float* __restrict__ cb,
                                                  const float* __restrict__ A32,
                                                  const float* __restrict__ B32,
                                                  const int* __restrict__ counter,
                                                  const int* __restrict__ list,
                                                  const float* __restrict__ vlist,
                                                  unsigned long long* __restrict__ cell) {
    __shared__ float zs[8][260];
    __shared__ int   pid[8];
    __shared__ float pvref[8];

    const int tid = threadIdx.x;
    int cnt = *counter;
    if (cnt > MAXREF) cnt = MAXREF;
    int i0 = blockIdx.x * 8;
    if (i0 >= cnt) return;

    if (tid < 8) {
        int idx   = i0 + tid;
        int valid = idx < cnt;
        pid[tid]   = list[valid ? idx : i0];
        pvref[tid] = valid ? vlist[idx] : -1e30f;
    }
    __syncthreads();

    {
        int px = tid >> 5;
        int dl = tid & 31;
        int n  = pid[px];
        int bb = n >> 10, hw = n & 1023;
        const float* zb = z + (size_t)bb * (D_ * HW_) + hw;
        #pragma unroll
        for (int j = 0; j < 8; ++j) {
            int d = dl * 8 + j;
            zs[px][d] = zb[(size_t)d * HW_];
        }
    }
    __syncthreads();

    const int kb = tid * 4;
    float a[4][8];
    #pragma unroll
    for (int jj = 0; jj < 4; ++jj)
        #pragma unroll
        for (int px = 0; px < 8; ++px) a[jj][px] = 0.f;

    for (int d4 = 0; d4 < 64; ++d4) {
        float4 c[4];
        #pragma unroll
        for (int jj = 0; jj < 4; ++jj)
            c[jj] = *reinterpret_cast<const float4*>(cb + (size_t)(kb + jj) * D_ + d4 * 4);
        #pragma unroll
        for (int px = 0; px < 8; ++px) {
            float4 z4 = *reinterpret_cast<const float4*>(&zs[px][d4 * 4]);
            #pragma unroll
            for (int jj = 0; jj < 4; ++jj) {
                a[jj][px] = fmaf(c[jj].x, z4.x, a[jj][px]);
                a[jj][px] = fmaf(c[jj].y, z4.y, a[jj][px]);
                a[jj][px] = fmaf(c[jj].z, z4.z, a[jj][px]);
                a[jj][px] = fmaf(c[jj].w, z4.w, a[jj][px]);
            }
        }
    }

    #pragma unroll
    for (int jj = 0; jj < 4; ++jj) {
        int k = kb + jj;
        float hb = 0.5f * B32[k];
        #pragma unroll
        for (int px = 0; px < 8; ++px) {
            float s = hb - a[jj][px];
            if (s - pvref[px] < RMARGIN) {
                int n = pid[px];
                const float4* crow = reinterpret_cast<const float4*>(cb + (size_t)k * D_);
                double a0 = 0.0, a1 = 0.0, a2 = 0.0, a3 = 0.0;
                for (int d4 = 0; d4 < 64; ++d4) {
                    float4 c4 = crow[d4];
                    a0 = fma((double)c4.x, (double)zs[px][d4 * 4 + 0], a0);
                    a1 = fma((double)c4.y, (double)zs[px][d4 * 4 + 1], a1);
                    a2 = fma((double)c4.z, (double)zs[px][d4 * 4 + 2], a2);
                    a3 = fma((double)c4.w, (double)zs[px][d4 * 4 + 3], a3);
                }
                float C32 = (float)((a0 + a1) + (a2 + a3));
                float d32 = __fsub_rn(__fadd_rn(A32[n], B32[k]), __fadd_rn(C32, C32));
                unsigned long long key =
                    ((unsigned long long)__float_as_uint(d32) << 32) | (unsigned)k;
                atomicMin(&cell[i0 + px], key);
            }
        }
    }
}

// ---------------------------------------------------------------------------
__global__ __launch_bounds__(256) void finalize_kernel(const int* __restrict__ counter,
                                                       const int* __restrict__ list,
                                                       const unsigned long long* __restrict__ cell,
                                                       float* __restrict__ oidx) {
    int cnt = *counter;
    if (cnt > MAXREF) cnt = MAXREF;
    for (int i = blockIdx.x * 256 + threadIdx.x; i < cnt; i += gridDim.x * 256) {
        oidx[list[i]] = (float)(unsigned)(cell[i] & 0xFFFFFFFFull);
    }
}

// ---------------------------------------------------------------------------
__global__ __launch_bounds__(256) void gather_kernel(const float* __restrict__ cb,
                                                     const float* __restrict__ oidx,
                                                     float* __restrict__ zq) {
    const int tid  = threadIdx.x;
    const int s_nl = tid & 63;
    const int s_dw = tid >> 6;
    const int p0   = blockIdx.x * 64;
    const int b    = p0 >> 10;
    const int hw0  = p0 & 1023;

    int idxn = (int)oidx[p0 + s_nl];
    const float4* crow = reinterpret_cast<const float4*>(cb + (size_t)idxn * D_);
    float* zqb = zq + (size_t)b * (D_ * HW_) + hw0;
    #pragma unroll
    for (int r = 0; r < 16; ++r) {
        int d4 = s_dw * 16 + r;
        float4 c4 = crow[d4];
        int d = d4 * 4;
        zqb[(size_t)(d + 0) * HW_ + s_nl] = c4.x;
        zqb[(size_t)(d + 1) * HW_ + s_nl] = c4.y;
        zqb[(size_t)(d + 2) * HW_ + s_nl] = c4.z;
        zqb[(size_t)(d + 3) * HW_ + s_nl] = c4.w;
    }
}

extern "C" void kernel_launch(void* const* d_in, const int* in_sizes, int n_in,
                              void* d_out, int out_size, void* d_ws, size_t ws_size,
                              hipStream_t stream) {
    const float* z  = (const float*)d_in[0];   // [32,256,32,32] fp32
    const float* cb = (const float*)d_in[1];   // [1024,256] fp32

    float* zq   = (float*)d_out;
    float* oidx = zq + (size_t)N_ * D_;

    char* ws = (char*)d_ws;
    int*                counter = (int*)(ws + 0);
    int*                list    = (int*)(ws + 1024);
    float*              B32     = (float*)(ws + 33792);
    float*              A32     = (float*)(ws + 37888);
    short*              cbAhi   = (short*)(ws + 168960);
    short*              cbAlo   = (short*)(ws + 693248);
    float*              vlist   = (float*)(ws + 1217536);
    unsigned long long* cell    = (unsigned long long*)(ws + 1250304);

    short8v* zBhi = (short8v*)zq;              // 16 MB
    short8v* zBlo = zBhi + 1048576;            // 16 MB

    prep_kernel<<<4357, 256, 0, stream>>>(z, cb, A32, B32, cbAhi, cbAlo,
                                          zBhi, zBlo, counter);
    vq_screen6<<<N_ / 64, 256, 0, stream>>>(
        zBhi, zBlo, (const short8v*)cbAhi, (const short8v*)cbAlo, B32,
        oidx, counter, list, vlist, cell);
    refine_np4<<<MAXREF / 8, 256, 0, stream>>>(z, cb, A32, B32, counter, list, vlist, cell);
    finalize_kernel<<<32, 256, 0, stream>>>(counter, list, cell, oidx);
    gather_kernel<<<N_ / 64, 256, 0, stream>>>(cb, oidx, zq);
}